// Round 9
// baseline (64.150 us; speedup 1.0000x reference)
//
#include <hip/hip_runtime.h>
#include <hip/hip_bf16.h>

#define NPTS  262144
#define CIN   16
#define COUT  32
#define NTAPS 27
#define BLK   512
#define DEPTH 12            // gathers in flight per wave (ring buffers)

typedef __attribute__((ext_vector_type(8)))  short short8v;   // 8 bf16 (4 VGPRs)
typedef __attribute__((ext_vector_type(16))) float f32x16;    // MFMA accumulator

// Prep: fb[0..15] = zero row; fb[16 + i] = bf16(feat[i]).  One float4/thread.
__global__ __launch_bounds__(256) void cvt_feat_kernel(
    const float* __restrict__ feat, __hip_bfloat16* __restrict__ fb)
{
    const int i = blockIdx.x * 256 + threadIdx.x;
    const float4 x = ((const float4*)feat)[i];
    __hip_bfloat162* o = (__hip_bfloat162*)(fb + CIN);   // shifted by zero row
    o[2 * i]     = __float22bfloat162_rn(float2{x.x, x.y});
    o[2 * i + 1] = __float22bfloat162_rn(float2{x.z, x.w});
    if (blockIdx.x == 0 && threadIdx.x < 2)
        ((int4*)fb)[threadIdx.x] = int4{0, 0, 0, 0};     // 32B zero row
}

// VAR=0: real kernel (R6 config, writes out).
// VAR=1: ablation probe — identical instruction stream but gather address
//        forced uniform (zero row) via min(id,-1); nid and acc kept live via
//        asm; no output store. Measures skeleton + uniform-hit gathers.
template<int VAR, bool USE_WS>
__global__ __launch_bounds__(BLK, 3) void sct_mfma_kernel(
    const float* __restrict__ feat,            // [N,16] fp32 (fallback)
    const __hip_bfloat16* __restrict__ featb,  // zero row + [N,16] bf16 (ws)
    const float* __restrict__ Wg,              // [27,16,32] fp32
    const float* __restrict__ bias,            // [32]
    const int*   __restrict__ nbr,             // [N,27]
    float*       __restrict__ out)             // [N,32]
{
    __shared__ short bpack[NTAPS * 512];       // 27648 B, one copy per 8 waves

    const int tid = threadIdx.x;
    for (int i = tid; i < NTAPS * 512; i += BLK) {
        const int tap  = i >> 9;
        const int r    = i & 511;
        const int ln   = r >> 3;
        const int e    = r & 7;
        const int cin  = ((ln >> 5) << 3) + e;
        const int cout = ln & 31;
        const __hip_bfloat16 h = __float2bfloat16(Wg[(tap * CIN + cin) * COUT + cout]);
        bpack[i] = *(const short*)&h;
    }
    __syncthreads();

    const int lane = tid & 63;
    const int wv   = tid >> 6;                        // 0..7
    const int p0   = blockIdx.x * 256 + wv * 32;      // this wave's 32 points
    const int prow = lane & 31;                       // A-row (point) / B-col (cout)
    const int g    = lane >> 5;                       // k-group
    const int* nb  = nbr + (long)(p0 + prow) * NTAPS;

    // all 27 neighbor ids up front: loads issued back-to-back, one wait
    int nid[NTAPS];
    #pragma unroll
    for (int q = 0; q < 6; ++q) {
        const int4 v = *(const int4*)(nb + 4 * q);
        nid[4*q+0] = v.x; nid[4*q+1] = v.y; nid[4*q+2] = v.z; nid[4*q+3] = v.w;
    }
    {
        const int2 v2 = *(const int2*)(nb + 24);
        nid[24] = v2.x; nid[25] = v2.y; nid[26] = nb[26];
    }

    f32x16 acc;
    {
        const float b = bias[prow];
        #pragma unroll
        for (int r2 = 0; r2 < 16; ++r2) acc[r2] = b;
    }

    short8v af[DEPTH];
    const __hip_bfloat16* fshift = featb + CIN;        // row -1 == zero row

    auto gather1 = [&](int t, short8v& dst) {
        if (USE_WS) {
            // VAR 0: real id. VAR 1: min(id,-1) -> always zero row (uniform
            // address, 100% L1 hit) while keeping nid live and the
            // instruction stream identical.
            const int id = (VAR == 0) ? nid[t] : (nid[t] < -1 ? nid[t] : -1);
            dst = *(const short8v*)(fshift + (long)id * CIN + g * 8);
        } else {
            const int id = nid[t];
            short8v a = {};
            if (id >= 0) {
                const float4* fp = (const float4*)(feat + (long)id * CIN + g * 8);
                const float4 x = fp[0];
                const float4 y = fp[1];
                union { short8v v; __hip_bfloat162 h[4]; } u;
                u.h[0] = __float22bfloat162_rn(float2{x.x, x.y});
                u.h[1] = __float22bfloat162_rn(float2{x.z, x.w});
                u.h[2] = __float22bfloat162_rn(float2{y.x, y.y});
                u.h[3] = __float22bfloat162_rn(float2{y.z, y.w});
                a = u.v;
            }
            dst = a;
        }
    };

    // prologue: 12 gathers in flight
    #pragma unroll
    for (int t = 0; t < DEPTH; ++t) gather1(t, af[t]);

    // steady state: consume tap t, refill slot with tap t+12
    #pragma unroll
    for (int t = 0; t < NTAPS; ++t) {
        const short8v bf = *(const short8v*)&bpack[(t << 9) + (lane << 3)];
        acc = __builtin_amdgcn_mfma_f32_32x32x16_bf16(af[t % DEPTH], bf, acc, 0, 0, 0);
        if (t + DEPTH < NTAPS) gather1(t + DEPTH, af[(t + DEPTH) % DEPTH]);
    }

    if (VAR == 0) {
        // D: col = lane&31 (cout), row = (reg&3) + 8*(reg>>2) + 4*(lane>>5)
        #pragma unroll
        for (int r2 = 0; r2 < 16; ++r2) {
            const int row = (r2 & 3) + 8 * (r2 >> 2) + 4 * g;
            out[(long)(p0 + row) * COUT + prow] = acc[r2];
        }
    } else {
        // keep acc (and the whole gather->MFMA chain) live without storing
        #pragma unroll
        for (int r2 = 0; r2 < 16; ++r2)
            asm volatile("" :: "v"(acc[r2]));
    }
}

extern "C" void kernel_launch(void* const* d_in, const int* in_sizes, int n_in,
                              void* d_out, int out_size, void* d_ws, size_t ws_size,
                              hipStream_t stream) {
    const float* feat = (const float*)d_in[0];
    const float* Wg   = (const float*)d_in[1];
    const float* bias = (const float*)d_in[2];
    const int*   nbr  = (const int*)d_in[3];
    float*       out  = (float*)d_out;

    const size_t need = (size_t)(NPTS + 1) * CIN * sizeof(__hip_bfloat16);  // 8 MB + row
    if (ws_size >= need) {
        __hip_bfloat16* fb = (__hip_bfloat16*)d_ws;
        cvt_feat_kernel<<<NPTS * CIN / 4 / 256, 256, 0, stream>>>(feat, fb);
        // V0: real kernel (correct output)
        sct_mfma_kernel<0, true><<<NPTS / 256, BLK, 0, stream>>>(
            feat, fb, Wg, bias, nbr, out);
        // V1: uniform-gather probe (same instruction stream, no stores)
        sct_mfma_kernel<1, true><<<NPTS / 256, BLK, 0, stream>>>(
            feat, fb, Wg, bias, nbr, out);
    } else {
        sct_mfma_kernel<0, false><<<NPTS / 256, BLK, 0, stream>>>(
            feat, nullptr, Wg, bias, nbr, out);
    }
}

// Round 10
// 44.569 us; speedup vs baseline: 1.4393x; 1.4393x over previous
//
#include <hip/hip_runtime.h>
#include <hip/hip_bf16.h>

#define NPTS  262144
#define CIN   16
#define COUT  32
#define NTAPS 27
#define BLK   512
#define DEPTH 12            // asm-pinned gathers in flight per wave

typedef __attribute__((ext_vector_type(8)))  short short8v;   // 8 bf16 (4 VGPRs)
typedef __attribute__((ext_vector_type(16))) float f32x16;    // MFMA accumulator

#define VMCNT(N) asm volatile("s_waitcnt vmcnt(" #N ")" ::: "memory")

// Prep: fb[0..15] = zero row; fb[16 + i] = bf16(feat[i]).  One float4/thread.
__global__ __launch_bounds__(256) void cvt_feat_kernel(
    const float* __restrict__ feat, __hip_bfloat16* __restrict__ fb)
{
    const int i = blockIdx.x * 256 + threadIdx.x;
    const float4 x = ((const float4*)feat)[i];
    __hip_bfloat162* o = (__hip_bfloat162*)(fb + CIN);   // shifted by zero row
    o[2 * i]     = __float22bfloat162_rn(float2{x.x, x.y});
    o[2 * i + 1] = __float22bfloat162_rn(float2{x.z, x.w});
    if (blockIdx.x == 0 && threadIdx.x < 2)
        ((int4*)fb)[threadIdx.x] = int4{0, 0, 0, 0};     // 32B zero row
}

// Per wave: 32 points x 32 cout via 27x v_mfma_f32_32x32x16_bf16.
// Symmetric A/B fragment packing (cin = (lane>>5)*8 + e both sides) so the HW
// k-permutation cancels — verified rounds 2-9.
// R9 found VGPR_Count=32: the compiler sank all nbr loads + gathers next to
// their MFMAs (serial ~700cy/tap chain) — the C-level ring never existed.
// This round pins the pipeline in inline asm: nid forced to VGPRs, gathers
// issued as ordered volatile global_load_dwordx4 into a 12-slot ring, counted
// s_waitcnt vmcnt(N) + sched_barrier(0) before each consuming MFMA.
template<bool USE_WS>
__global__ __launch_bounds__(BLK, 3) void sct_mfma_kernel(
    const float* __restrict__ feat,            // [N,16] fp32 (fallback)
    const __hip_bfloat16* __restrict__ featb,  // zero row + [N,16] bf16 (ws)
    const float* __restrict__ Wg,              // [27,16,32] fp32
    const float* __restrict__ bias,            // [32]
    const int*   __restrict__ nbr,             // [N,27]
    float*       __restrict__ out)             // [N,32]
{
    __shared__ short bpack[NTAPS * 512];       // 27648 B, one copy per 8 waves

    const int tid = threadIdx.x;
    for (int i = tid; i < NTAPS * 512; i += BLK) {
        const int tap  = i >> 9;
        const int r    = i & 511;
        const int ln   = r >> 3;
        const int e    = r & 7;
        const int cin  = ((ln >> 5) << 3) + e;
        const int cout = ln & 31;
        const __hip_bfloat16 h = __float2bfloat16(Wg[(tap * CIN + cin) * COUT + cout]);
        bpack[i] = *(const short*)&h;
    }
    __syncthreads();

    const int lane = tid & 63;
    const int wv   = tid >> 6;                        // 0..7
    const int p0   = blockIdx.x * 256 + wv * 32;      // this wave's 32 points
    const int prow = lane & 31;                       // A-row (point) / B-col (cout)
    const int g    = lane >> 5;                       // k-group
    const int* nb  = nbr + (long)(p0 + prow) * NTAPS;

    // all 27 neighbor ids, then FORCE them into VGPRs (un-sinkable)
    int nid[NTAPS];
    #pragma unroll
    for (int q = 0; q < 6; ++q) {
        const int4 v = *(const int4*)(nb + 4 * q);
        nid[4*q+0] = v.x; nid[4*q+1] = v.y; nid[4*q+2] = v.z; nid[4*q+3] = v.w;
    }
    {
        const int2 v2 = *(const int2*)(nb + 24);
        nid[24] = v2.x; nid[25] = v2.y; nid[26] = nb[26];
    }

    f32x16 acc;
    {
        const float b = bias[prow];
        #pragma unroll
        for (int r2 = 0; r2 < 16; ++r2) acc[r2] = b;
    }

    if (USE_WS) {
        const __hip_bfloat16* fshift = featb + CIN;    // row -1 == zero row
        const int elo = g * 8;

        // pin nid in registers NOW; afterwards the only outstanding vmem ops
        // are our asm gathers, so vmcnt counts are exact
        #pragma unroll
        for (int t = 0; t < NTAPS; ++t) asm volatile("" : "+v"(nid[t]));
        VMCNT(0);

        short8v af[DEPTH];
        auto issue = [&](int t, short8v& dst) {
            const void* ap = (const void*)(fshift + (long)nid[t] * CIN + elo);
            asm volatile("global_load_dwordx4 %0, %1, off"
                         : "=&v"(dst) : "v"(ap) : "memory");
        };

        #pragma unroll
        for (int t = 0; t < DEPTH; ++t) issue(t, af[t]);   // 12 in flight

        #pragma unroll
        for (int t = 0; t < NTAPS; ++t) {
            const int rem = (NTAPS - 1 - t < DEPTH - 1) ? (NTAPS - 1 - t)
                                                        : (DEPTH - 1);
            switch (rem) {                                  // folds: t is constant
                case 11: VMCNT(11); break;
                case 10: VMCNT(10); break;
                case  9: VMCNT(9);  break;
                case  8: VMCNT(8);  break;
                case  7: VMCNT(7);  break;
                case  6: VMCNT(6);  break;
                case  5: VMCNT(5);  break;
                case  4: VMCNT(4);  break;
                case  3: VMCNT(3);  break;
                case  2: VMCNT(2);  break;
                case  1: VMCNT(1);  break;
                default: VMCNT(0);  break;
            }
            __builtin_amdgcn_sched_barrier(0);              // rule 18: fence MFMA
            const short8v bf = *(const short8v*)&bpack[(t << 9) + (lane << 3)];
            acc = __builtin_amdgcn_mfma_f32_32x32x16_bf16(af[t % DEPTH], bf, acc, 0, 0, 0);
            if (t + DEPTH < NTAPS) issue(t + DEPTH, af[(t + DEPTH) % DEPTH]);
        }
    } else {
        // fallback: masked fp32 gathers + in-reg cvt (verified rounds 2-9)
        #pragma unroll
        for (int t = 0; t < NTAPS; ++t) {
            const int id = nid[t];
            short8v a = {};
            if (id >= 0) {
                const float4* fp = (const float4*)(feat + (long)id * CIN + g * 8);
                const float4 x = fp[0];
                const float4 y = fp[1];
                union { short8v v; __hip_bfloat162 h[4]; } u;
                u.h[0] = __float22bfloat162_rn(float2{x.x, x.y});
                u.h[1] = __float22bfloat162_rn(float2{x.z, x.w});
                u.h[2] = __float22bfloat162_rn(float2{y.x, y.y});
                u.h[3] = __float22bfloat162_rn(float2{y.z, y.w});
                a = u.v;
            }
            const short8v bf = *(const short8v*)&bpack[(t << 9) + (lane << 3)];
            acc = __builtin_amdgcn_mfma_f32_32x32x16_bf16(a, bf, acc, 0, 0, 0);
        }
    }

    // D: col = lane&31 (cout), row = (reg&3) + 8*(reg>>2) + 4*(lane>>5) (point)
    #pragma unroll
    for (int r2 = 0; r2 < 16; ++r2) {
        const int row = (r2 & 3) + 8 * (r2 >> 2) + 4 * g;
        out[(long)(p0 + row) * COUT + prow] = acc[r2];
    }
}

extern "C" void kernel_launch(void* const* d_in, const int* in_sizes, int n_in,
                              void* d_out, int out_size, void* d_ws, size_t ws_size,
                              hipStream_t stream) {
    const float* feat = (const float*)d_in[0];
    const float* Wg   = (const float*)d_in[1];
    const float* bias = (const float*)d_in[2];
    const int*   nbr  = (const int*)d_in[3];
    float*       out  = (float*)d_out;

    const size_t need = (size_t)(NPTS + 1) * CIN * sizeof(__hip_bfloat16);  // 8 MB + row
    if (ws_size >= need) {
        __hip_bfloat16* fb = (__hip_bfloat16*)d_ws;
        cvt_feat_kernel<<<NPTS * CIN / 4 / 256, 256, 0, stream>>>(feat, fb);
        sct_mfma_kernel<true><<<NPTS / 256, BLK, 0, stream>>>(feat, fb, Wg, bias, nbr, out);
    } else {
        sct_mfma_kernel<false><<<NPTS / 256, BLK, 0, stream>>>(feat, nullptr, Wg, bias, nbr, out);
    }
}